// Round 1
// 652.893 us; speedup vs baseline: 1.4534x; 1.4534x over previous
//
#include <hip/hip_runtime.h>
#include <hip/hip_bf16.h>

// SCConv: bin all 7 ops once into 128-row buckets via run-reserved scatter,
// 3 fused powcat-GEMMs now on MFMA (split-bf16 3-term: xh*wh + xh*wl + xl*wh
// gives fp32-grade accuracy), then one bucketed spmm per output segment.

#define RPB 128
#define CAP 2048
#define COL_MASK 0x7FFFFu
#define LROW_SH 19
#define DID_SH 26
#define MAXNB 4352
#define BIN_GRID 192

typedef __attribute__((ext_vector_type(8))) short short8;
typedef __attribute__((ext_vector_type(4))) float f32x4;

__device__ __forceinline__ int   ntld_i(const int* p)   { return __builtin_nontemporal_load(p); }
__device__ __forceinline__ float ntld_f(const float* p) { return __builtin_nontemporal_load(p); }
__device__ __forceinline__ float4 ntld_f4(const float* p) {
    const unsigned long long* q = (const unsigned long long*)p;
    unsigned long long a = __builtin_nontemporal_load(q);
    unsigned long long b = __builtin_nontemporal_load(q + 1);
    float4 v;
    v.x = __uint_as_float((unsigned)a);
    v.y = __uint_as_float((unsigned)(a >> 32));
    v.z = __uint_as_float((unsigned)b);
    v.w = __uint_as_float((unsigned)(b >> 32));
    return v;
}
__device__ __forceinline__ void ntst_f4(float* p, float4 v) {
    unsigned long long a = (unsigned long long)__float_as_uint(v.x)
                         | ((unsigned long long)__float_as_uint(v.y) << 32);
    unsigned long long b = (unsigned long long)__float_as_uint(v.z)
                         | ((unsigned long long)__float_as_uint(v.w) << 32);
    unsigned long long* q = (unsigned long long*)p;
    __builtin_nontemporal_store(a, q);
    __builtin_nontemporal_store(b, q + 1);
}

// ---------------- bf16 helpers (RNE) --------------------------------------
__device__ __forceinline__ unsigned short f2bf(float f) {
    unsigned u = __float_as_uint(f);
    unsigned r = u + 0x7FFFu + ((u >> 16) & 1u);
    return (unsigned short)(r >> 16);
}

__device__ __forceinline__ void split8(float4 a0, float4 a1, short8& hi, short8& lo) {
    float v[8] = {a0.x, a0.y, a0.z, a0.w, a1.x, a1.y, a1.z, a1.w};
    #pragma unroll
    for (int e = 0; e < 8; ++e) {
        unsigned short h = f2bf(v[e]);
        float hf = __uint_as_float((unsigned)h << 16);
        hi[e] = (short)h;
        lo[e] = (short)f2bf(v[e] - hf);
    }
}

// ---------------- W -> MFMA B-fragment precompute (once per launch) -------
// Frag layout per set (16384 ushorts = 32KB):
//   [kk(4)][nf(4)][h(2: hi,lo)][lane(64)][e(8)]
// lane l, elem e: k = kk*32 + 8*(l>>4) + e ; col = nf*16 + (l&15)
struct WAll { const float* w[7]; };

__global__ __launch_bounds__(256) void winit(WAll wa, unsigned short* __restrict__ frags)
{
    const int s = blockIdx.x;
    const float* __restrict__ W = wa.w[s];
    unsigned short* __restrict__ out = frags + (size_t)s * 16384;
    for (int slot = threadIdx.x; slot < 1024; slot += 256) {
        const int l  = slot & 63;
        const int nf = (slot >> 6) & 3;
        const int kk = slot >> 8;
        const int col = nf * 16 + (l & 15);
        const int kb  = kk * 32 + 8 * (l >> 4);
        short8 vh, vl;
        #pragma unroll
        for (int e = 0; e < 8; ++e) {
            float w = W[(size_t)(kb + e) * 64 + col];
            unsigned short h = f2bf(w);
            float hf = __uint_as_float((unsigned)h << 16);
            vh[e] = (short)h;
            vl[e] = (short)f2bf(w - hf);
        }
        *(short8*)(out + ((size_t)((kk * 4 + nf) * 2 + 0) * 64 + l) * 8) = vh;
        *(short8*)(out + ((size_t)((kk * 4 + nf) * 2 + 1) * 64 + l) * 8) = vl;
    }
}

// ---------------- MFMA powcat-GEMM (up to 3 weight sets per X) ------------
__device__ __forceinline__ void mfma_set(
    const short8 Ah[4], const short8 Al[4],
    const unsigned short* __restrict__ F, const float* __restrict__ bias,
    unsigned short* __restrict__ D, int nrows, int row0w, int l)
{
    const int lg = l >> 4, lr = l & 15;
    const short8* __restrict__ Fv = (const short8*)F;
    f32x4 acc[4];
    #pragma unroll
    for (int nf = 0; nf < 4; ++nf) {
        float b = bias[nf * 16 + lr];
        f32x4 bi = {b, b, b, b};
        acc[nf] = bi;
    }
    #pragma unroll
    for (int kk = 0; kk < 4; ++kk) {
        #pragma unroll
        for (int nf = 0; nf < 4; ++nf) {
            short8 bh = Fv[((kk * 4 + nf) * 2 + 0) * 64 + l];
            short8 bl = Fv[((kk * 4 + nf) * 2 + 1) * 64 + l];
            acc[nf] = __builtin_amdgcn_mfma_f32_16x16x32_bf16(Ah[kk], bh, acc[nf], 0, 0, 0);
            acc[nf] = __builtin_amdgcn_mfma_f32_16x16x32_bf16(Al[kk], bh, acc[nf], 0, 0, 0);
            acc[nf] = __builtin_amdgcn_mfma_f32_16x16x32_bf16(Ah[kk], bl, acc[nf], 0, 0, 0);
        }
    }
    #pragma unroll
    for (int nf = 0; nf < 4; ++nf) {
        #pragma unroll
        for (int j = 0; j < 4; ++j) {
            int row = row0w + lg * 4 + j;   // C/D: col=lane&15, row=4*(lane>>4)+reg
            if (row < nrows)
                D[(size_t)row * 64 + nf * 16 + lr] = f2bf(acc[nf][j]);
        }
    }
}

__global__ __launch_bounds__(256) void gemm_powcat_mfma(
    const float* __restrict__ X, int nrows, int nsets,
    const unsigned short* __restrict__ F0, const float* __restrict__ b0, unsigned short* __restrict__ D0,
    const unsigned short* __restrict__ F1, const float* __restrict__ b1, unsigned short* __restrict__ D1,
    const unsigned short* __restrict__ F2, const float* __restrict__ b2, unsigned short* __restrict__ D2)
{
    __shared__ float Xs[64][68];   // pad stride 68 -> balanced LDS banks
    const int tid = threadIdx.x;
    const int row0 = blockIdx.x * 64;

    #pragma unroll
    for (int it = 0; it < 4; ++it) {
        int idx = tid + it * 256;
        int r = idx >> 4, c4 = idx & 15;
        float4 v = make_float4(0.f, 0.f, 0.f, 0.f);
        if (row0 + r < nrows)
            v = ntld_f4(X + (size_t)(row0 + r) * 64 + c4 * 4);
        *(float4*)&Xs[r][c4 * 4] = v;
    }
    __syncthreads();

    const int w = tid >> 6, l = tid & 63;
    const int lg = l >> 4, lr = l & 15;

    // A-frags (shared across all weight sets): powcat K=128 = [X | X^2]
    // lane l: row = w*16 + (l&15), k = kk*32 + 8*(l>>4) + e (contiguous 8)
    short8 Ah[4], Al[4];
    #pragma unroll
    for (int kk = 0; kk < 4; ++kk) {
        const float* p = &Xs[w * 16 + lr][(kk & 1) * 32 + 8 * lg];
        float4 a0 = *(const float4*)p;
        float4 a1 = *(const float4*)(p + 4);
        if (kk >= 2) {
            a0.x *= a0.x; a0.y *= a0.y; a0.z *= a0.z; a0.w *= a0.w;
            a1.x *= a1.x; a1.y *= a1.y; a1.z *= a1.z; a1.w *= a1.w;
        }
        split8(a0, a1, Ah[kk], Al[kk]);
    }

    const int row0w = row0 + w * 16;
    mfma_set(Ah, Al, F0, b0, D0, nrows, row0w, l);
    if (nsets > 1) mfma_set(Ah, Al, F1, b1, D1, nrows, row0w, l);
    if (nsets > 2) mfma_set(Ah, Al, F2, b2, D2, nrows, row0w, l);
}

// ---------------- 7-slot flat COO view ------------------------------------
struct Bin7 {
    const int *r0, *r1, *r2, *r3, *r4, *r5, *r6;
    const int *c0, *c1, *c2, *c3, *c4, *c5, *c6;
    const float *v0, *v1, *v2, *v3, *v4, *v5, *v6;
    int p1, p2, p3, p4, p5, p6, p7;   // cumulative prefix ends
    int t0, t1, t2, t3, t4, t5, t6;   // bucket-tile base per slot
};

struct Ent { int r; int tb; unsigned cw; float v; };

template<bool FULL>
__device__ __forceinline__ Ent decode(const Bin7& B, int i) {
    Ent e;
    if (i < B.p1) {
        int li = i;
        e.r = ntld_i(B.r0 + li); e.tb = B.t0;
        if (FULL) { e.cw = (unsigned)ntld_i(B.c0 + li) | (0u << DID_SH); e.v = ntld_f(B.v0 + li); }
    } else if (i < B.p2) {
        int li = i - B.p1;
        e.r = ntld_i(B.r1 + li); e.tb = B.t1;
        if (FULL) { e.cw = (unsigned)ntld_i(B.c1 + li) | (1u << DID_SH); e.v = ntld_f(B.v1 + li); }
    } else if (i < B.p3) {
        int li = i - B.p2;
        e.r = ntld_i(B.r2 + li); e.tb = B.t2;
        if (FULL) { e.cw = (unsigned)ntld_i(B.c2 + li) | (2u << DID_SH); e.v = ntld_f(B.v2 + li); }
    } else if (i < B.p4) {
        int li = i - B.p3;
        e.r = ntld_i(B.r3 + li); e.tb = B.t3;
        if (FULL) { e.cw = (unsigned)ntld_i(B.c3 + li) | (3u << DID_SH); e.v = ntld_f(B.v3 + li); }
    } else if (i < B.p5) {
        int li = i - B.p4;
        e.r = ntld_i(B.r4 + li); e.tb = B.t4;
        if (FULL) { e.cw = (unsigned)ntld_i(B.c4 + li) | (4u << DID_SH); e.v = ntld_f(B.v4 + li); }
    } else if (i < B.p6) {
        int li = i - B.p5;
        e.r = ntld_i(B.r5 + li); e.tb = B.t5;
        if (FULL) { e.cw = (unsigned)ntld_i(B.c5 + li) | (5u << DID_SH); e.v = ntld_f(B.v5 + li); }
    } else {
        int li = i - B.p6;
        e.r = ntld_i(B.r6 + li); e.tb = B.t6;
        if (FULL) { e.cw = (unsigned)ntld_i(B.c6 + li) | (6u << DID_SH); e.v = ntld_f(B.v6 + li); }
    }
    return e;
}

// ---------------- histogram with LDS pre-aggregation ----------------------
__global__ __launch_bounds__(1024) void bhist_lds(
    Bin7 B, int* __restrict__ bcount, int NBtot, int chunk)
{
    __shared__ int h[MAXNB];
    for (int i = threadIdx.x; i < NBtot; i += 1024) h[i] = 0;
    __syncthreads();
    const int s = blockIdx.x * chunk;
    int e = s + chunk;  if (e > B.p7) e = B.p7;
    for (int i = s + threadIdx.x; i < e; i += 1024) {
        Ent en = decode<false>(B, i);
        atomicAdd(&h[en.tb + (en.r >> 7)], 1);
    }
    __syncthreads();
    for (int i = threadIdx.x; i < NBtot; i += 1024)
        if (h[i]) atomicAdd(&bcount[i], h[i]);
}

// ---------------- run-reserved scatter ------------------------------------
__global__ __launch_bounds__(1024) void scatter_runs(
    Bin7 B, int* __restrict__ bcur, uint2* __restrict__ bpay,
    int NBtot, int chunk)
{
    __shared__ int lbase[MAXNB];
    __shared__ int lcur[MAXNB];
    for (int i = threadIdx.x; i < NBtot; i += 1024) lcur[i] = 0;
    __syncthreads();
    const int s = blockIdx.x * chunk;
    int e = s + chunk;  if (e > B.p7) e = B.p7;

    // pass 1: local histogram
    for (int i = s + threadIdx.x; i < e; i += 1024) {
        Ent en = decode<false>(B, i);
        atomicAdd(&lcur[en.tb + (en.r >> 7)], 1);
    }
    __syncthreads();
    // reserve one run per non-empty bucket
    for (int i = threadIdx.x; i < NBtot; i += 1024) {
        int c = lcur[i];
        lbase[i] = c ? atomicAdd(&bcur[i], c) : 0;
        lcur[i] = 0;
    }
    __syncthreads();
    // pass 2: write entries (chunk is L3-hot from pass 1)
    for (int i = s + threadIdx.x; i < e; i += 1024) {
        Ent en = decode<true>(B, i);
        int b = en.tb + (en.r >> 7);
        int pos = lbase[b] + atomicAdd(&lcur[b], 1);
        unsigned w = en.cw | ((unsigned)(en.r & 127) << LROW_SH);
        bpay[pos] = make_uint2(w, __float_as_uint(en.v));
    }
}

// ---------------- shfl-based single-block exclusive scan ------------------
__global__ __launch_bounds__(1024) void scan_small(
    const int* __restrict__ in, int* __restrict__ boff,
    int* __restrict__ bcur, int n)
{
    __shared__ int wsum[16];
    __shared__ int carry;
    const int tid = threadIdx.x, lane = tid & 63, wv = tid >> 6;
    if (tid == 0) carry = 0;
    __syncthreads();
    for (int base = 0; base < n; base += 4096) {
        int i = base + tid * 4;
        int v0 = (i + 0 < n) ? in[i + 0] : 0;
        int v1 = (i + 1 < n) ? in[i + 1] : 0;
        int v2 = (i + 2 < n) ? in[i + 2] : 0;
        int v3 = (i + 3 < n) ? in[i + 3] : 0;
        int tsum = v0 + v1 + v2 + v3;
        int x = tsum;
        #pragma unroll
        for (int off = 1; off < 64; off <<= 1) {
            int y = __shfl_up(x, off);
            if (lane >= off) x += y;
        }
        if (lane == 63) wsum[wv] = x;
        int c0 = carry;
        __syncthreads();
        if (tid < 16) {
            int ss = wsum[tid];
            #pragma unroll
            for (int off = 1; off < 16; off <<= 1) {
                int y = __shfl_up(ss, off, 16);
                if (tid >= off) ss += y;
            }
            wsum[tid] = ss;
        }
        __syncthreads();
        int wpre = (wv == 0) ? 0 : wsum[wv - 1];
        int excl = c0 + wpre + (x - tsum);
        if (i + 0 < n) { boff[i + 0] = excl; bcur[i + 0] = excl; } excl += v0;
        if (i + 1 < n) { boff[i + 1] = excl; bcur[i + 1] = excl; } excl += v1;
        if (i + 2 < n) { boff[i + 2] = excl; bcur[i + 2] = excl; } excl += v2;
        if (i + 3 < n) { boff[i + 3] = excl; bcur[i + 3] = excl; }
        __syncthreads();
        if (tid == 0) carry = c0 + wsum[15];
        __syncthreads();
    }
}

// ---------------- bucketed SpMM (single segment per bucket) ---------------
__global__ __launch_bounds__(256) void spmm_fused7(
    const uint2* __restrict__ bpay, const int* __restrict__ boff,
    const int* __restrict__ bend,
    const unsigned short* __restrict__ d0, const unsigned short* __restrict__ d1,
    const unsigned short* __restrict__ d2, const unsigned short* __restrict__ d3,
    const unsigned short* __restrict__ d4, const unsigned short* __restrict__ d5,
    const unsigned short* __restrict__ d6,
    float* __restrict__ out, int tile0, int nrows,
    int firstWrite, int doRelu, float scale, int didMask)
{
    __shared__ uint2 pay[CAP];            // 16 KB
    __shared__ unsigned short sidx[CAP];  // 4 KB
    __shared__ int lcount[128], loff[128], lcur[128];
    __shared__ int s_w0;
    __shared__ const unsigned short* dptr[8];

    const int tid = threadIdx.x;
    const int t = tile0 + blockIdx.x;

    if (tid == 0) {
        dptr[0] = d0; dptr[1] = d1; dptr[2] = d2; dptr[3] = d3;
        dptr[4] = d4; dptr[5] = d5; dptr[6] = d6; dptr[7] = d0;
    }
    __syncthreads();

    const int seg0  = boff[t];
    const int total = bend[t] - seg0;
    const int nchunks = (total + CAP - 1) / CAP;
    const int qw = tid >> 4, l = tid & 15;
    const int row0 = blockIdx.x * RPB;

    float4 acc[8];
    #pragma unroll
    for (int rr = 0; rr < 8; ++rr) acc[rr] = make_float4(0.f, 0.f, 0.f, 0.f);

    for (int c = 0; c < nchunks; ++c) {
        if (tid < 128) lcount[tid] = 0;
        __syncthreads();

        const int cbase = c * CAP;
        int ccnt = total - cbase;
        if (ccnt > CAP) ccnt = CAP;

        for (int i = tid; i < ccnt; i += 256) {
            unsigned long long pv = __builtin_nontemporal_load(
                (const unsigned long long*)(bpay + seg0 + cbase + i));
            uint2 p = make_uint2((unsigned)pv, (unsigned)(pv >> 32));
            pay[i] = p;
            atomicAdd(&lcount[(p.x >> LROW_SH) & 127], 1);
        }
        __syncthreads();

        int xv = 0;
        if (tid < 128) xv = lcount[tid];
        #pragma unroll
        for (int off = 1; off < 64; off <<= 1) {
            int y = __shfl_up(xv, off);
            if ((tid & 63) >= off) xv += y;
        }
        if (tid == 63) s_w0 = xv;
        __syncthreads();
        if (tid < 128) {
            int incl = xv + ((tid >= 64) ? s_w0 : 0);
            loff[tid] = incl - lcount[tid];
            lcur[tid] = incl - lcount[tid];
        }
        __syncthreads();

        for (int i = tid; i < ccnt; i += 256) {
            int lr = (pay[i].x >> LROW_SH) & 127;
            int pos = atomicAdd(&lcur[lr], 1);
            sidx[pos] = (unsigned short)i;
        }
        __syncthreads();

        #pragma unroll
        for (int rr = 0; rr < 8; ++rr) {
            int lr = rr * 16 + qw;
            int ss = loff[lr], ee = ss + lcount[lr];
            float4 a = acc[rr];
            for (int j = ss; j < ee; ++j) {
                uint2 p = pay[sidx[j]];
                int did = (int)(p.x >> DID_SH) & 7;
                if (!((didMask >> did) & 1)) continue;
                int col = p.x & COL_MASK;
                float v = __uint_as_float(p.y);
                const uint2* Dg = reinterpret_cast<const uint2*>(dptr[did]);
                uint2 d = Dg[(size_t)col * 16 + l];
                a.x = fmaf(v, __uint_as_float((d.x & 0xFFFFu) << 16), a.x);
                a.y = fmaf(v, __uint_as_float(d.x & 0xFFFF0000u), a.y);
                a.z = fmaf(v, __uint_as_float((d.y & 0xFFFFu) << 16), a.z);
                a.w = fmaf(v, __uint_as_float(d.y & 0xFFFF0000u), a.w);
            }
            acc[rr] = a;
        }
        __syncthreads();
    }

    #pragma unroll
    for (int rr = 0; rr < 8; ++rr) {
        int lr = rr * 16 + qw;
        int row = row0 + lr;
        if (row < nrows) {
            float* o = out + (size_t)row * 64 + l * 4;
            float4 a = acc[rr];
            if (!firstWrite) {
                float4 cur = *reinterpret_cast<float4*>(o);
                a.x += cur.x; a.y += cur.y; a.z += cur.z; a.w += cur.w;
            }
            if (doRelu) {
                a.x = fmaxf(a.x, 0.f) * scale;
                a.y = fmaxf(a.y, 0.f) * scale;
                a.z = fmaxf(a.z, 0.f) * scale;
                a.w = fmaxf(a.w, 0.f) * scale;
            }
            ntst_f4(o, a);
        }
    }
}

extern "C" void kernel_launch(void* const* d_in, const int* in_sizes, int n_in,
                              void* d_out, int out_size, void* d_ws, size_t ws_size,
                              hipStream_t stream)
{
    const float* X0 = (const float*)d_in[0];
    const float* X1 = (const float*)d_in[1];
    const float* X2 = (const float*)d_in[2];
    const int N0 = in_sizes[0] / 64;
    const int N1 = in_sizes[1] / 64;
    const int N2 = in_sizes[2] / 64;

    auto Wp = [&](int i) { return (const float*)d_in[24 + 2 * i]; };
    auto bp = [&](int i) { return (const float*)d_in[25 + 2 * i]; };
    auto Sr = [&](int i) { return (const int*)d_in[3 + 3 * i]; };
    auto Sc = [&](int i) { return (const int*)d_in[4 + 3 * i]; };
    auto Sv = [&](int i) { return (const float*)d_in[5 + 3 * i]; };
    auto Sn = [&](int i) { return in_sizes[3 + 3 * i]; };

    const size_t offY1 = (size_t)N0 * 64;
    const size_t offY2 = (size_t)(N0 + N1) * 64;
    const float TH = 1.0f / 3.0f;

    const int NB0 = (N0 + RPB - 1) / RPB;
    const int NB1 = (N1 + RPB - 1) / RPB;
    const int NB2 = (N2 + RPB - 1) / RPB;

    float* out = (float*)d_out;
    auto align256 = [](size_t x) { return (x + 255) & ~(size_t)255; };

    // -------- W fragment precompute (all 7 sets, once) --------
    const size_t FRAG_SET = 16384;  // ushorts per set (32 KB)
    const size_t fragB = align256(7 * FRAG_SET * sizeof(unsigned short));
    if (ws_size <= fragB) return;   // pathological; cannot run
    unsigned short* wfrags = (unsigned short*)d_ws;
    char* ws = (char*)d_ws + fragB;
    const size_t ws_avail = ws_size - fragB;
    auto wf = [&](int i) { return wfrags + (size_t)i * FRAG_SET; };

    WAll wa;
    for (int i = 0; i < 7; ++i) wa.w[i] = Wp(i);
    winit<<<7, 256, 0, stream>>>(wa, wfrags);

    // -------- tier 1: everything at once --------
    const int NBall = NB0 + NB1 + NB2;
    const int nnzAll = Sn(0)+Sn(1)+Sn(2)+Sn(3)+Sn(4)+Sn(5)+Sn(6);
    const size_t payT1 = align256((size_t)nnzAll * sizeof(uint2));
    const size_t cntT1 = align256((size_t)NBall * sizeof(int));
    const size_t denseT1 = ((size_t)2*N0 + 3*N1 + 2*N2) * 64 * sizeof(unsigned short);
    const size_t needT1 = payT1 + 3 * cntT1 + denseT1;

    if (ws_avail >= needT1 && NBall <= MAXNB) {
        uint2* bpay   = (uint2*)ws;
        int*   bcount = (int*)(ws + payT1);
        int*   boff   = (int*)(ws + payT1 + cntT1);
        int*   bcur   = (int*)(ws + payT1 + 2 * cntT1);
        unsigned short* db = (unsigned short*)(ws + payT1 + 3 * cntT1);
        unsigned short* dn2n = db;
        unsigned short* de2n = dn2n + (size_t)N0 * 64;
        unsigned short* dn2e = de2n + (size_t)N1 * 64;
        unsigned short* de2e = dn2e + (size_t)N0 * 64;
        unsigned short* dt2e = de2e + (size_t)N1 * 64;
        unsigned short* de2t = dt2e + (size_t)N2 * 64;
        unsigned short* dt2t = de2t + (size_t)N1 * 64;

        Bin7 B;
        // did: 0 n2n(L0) 1 e2n(D1invB1) 2 n2e(D2B1TD1inv) 3 e2e(L1) 4 t2e(B2D3) 5 e2t(B2TD2inv) 6 t2t(L2)
        B.r0 = Sr(0); B.c0 = Sc(0); B.v0 = Sv(0);
        B.r1 = Sr(3); B.c1 = Sc(3); B.v1 = Sv(3);
        B.r2 = Sr(4); B.c2 = Sc(4); B.v2 = Sv(4);
        B.r3 = Sr(1); B.c3 = Sc(1); B.v3 = Sv(1);
        B.r4 = Sr(6); B.c4 = Sc(6); B.v4 = Sv(6);
        B.r5 = Sr(5); B.c5 = Sc(5); B.v5 = Sv(5);
        B.r6 = Sr(2); B.c6 = Sc(2); B.v6 = Sv(2);
        B.p1 = Sn(0);
        B.p2 = B.p1 + Sn(3);
        B.p3 = B.p2 + Sn(4);
        B.p4 = B.p3 + Sn(1);
        B.p5 = B.p4 + Sn(6);
        B.p6 = B.p5 + Sn(5);
        B.p7 = B.p6 + Sn(2);
        B.t0 = 0;   B.t1 = 0;
        B.t2 = NB0; B.t3 = NB0; B.t4 = NB0;
        B.t5 = NB0 + NB1; B.t6 = NB0 + NB1;

        const int chunk = (B.p7 + BIN_GRID - 1) / BIN_GRID;
        hipMemsetAsync(bcount, 0, (size_t)NBall * sizeof(int), stream);
        bhist_lds<<<BIN_GRID, 1024, 0, stream>>>(B, bcount, NBall, chunk);
        scan_small<<<1, 1024, 0, stream>>>(bcount, boff, bcur, NBall);
        scatter_runs<<<BIN_GRID, 1024, 0, stream>>>(B, bcur, bpay, NBall, chunk);

        gemm_powcat_mfma<<<(N0 + 63) / 64, 256, 0, stream>>>(
            X0, N0, 2,
            wf(0), bp(0), dn2n,
            wf(1), bp(1), dn2e,
            wf(0), bp(0), dn2n);
        gemm_powcat_mfma<<<(N1 + 63) / 64, 256, 0, stream>>>(
            X1, N1, 3,
            wf(3), bp(3), de2n,
            wf(2), bp(2), de2e,
            wf(4), bp(4), de2t);
        gemm_powcat_mfma<<<(N2 + 63) / 64, 256, 0, stream>>>(
            X2, N2, 2,
            wf(5), bp(5), dt2e,
            wf(6), bp(6), dt2t,
            wf(5), bp(5), dt2e);

        spmm_fused7<<<NB0, 256, 0, stream>>>(bpay, boff, bcur,
            dn2n, de2n, dn2e, de2e, dt2e, de2t, dt2t,
            out, 0, N0, 1, 1, 0.5f, 0x7F);
        spmm_fused7<<<NB1, 256, 0, stream>>>(bpay, boff, bcur,
            dn2n, de2n, dn2e, de2e, dt2e, de2t, dt2t,
            out + offY1, NB0, N1, 1, 1, TH, 0x7F);
        spmm_fused7<<<NB2, 256, 0, stream>>>(bpay, boff, bcur,
            dn2n, de2n, dn2e, de2e, dt2e, de2t, dt2t,
            out + offY2, NB0 + NB1, N2, 1, 1, 0.5f, 0x7F);
        return;
    }

    // -------- tier 2: two-group phased layout (same kernels) --------
    const int NBtotA = NB0 + NB2;
    const int NBmax = NBtotA > NB1 ? NBtotA : NB1;
    const int nnzA = Sn(0) + Sn(3) + Sn(5) + Sn(2);
    const int nnzB = Sn(4) + Sn(6) + Sn(1);
    const int nnzMax = nnzA > nnzB ? nnzA : nnzB;

    const size_t payB = align256((size_t)nnzMax * sizeof(uint2));
    const size_t cntB = align256((size_t)NBmax * sizeof(int));
    const size_t denseOff = payB + 3 * cntB;

    uint2* bpay   = (uint2*)ws;
    int*   bcount = (int*)(ws + payB);
    int*   boff   = (int*)(ws + payB + cntB);
    int*   bcur   = (int*)(ws + payB + 2 * cntB);
    unsigned short* dense = (unsigned short*)(ws + denseOff);

    const size_t need_full = denseOff +
        ((size_t)N0 + N2 + N1) * 64 * sizeof(unsigned short);
    const bool fullB = (ws_avail >= need_full);

    // ---- group A: did 0=n2n(Y0) 1=e2n(Y0) 2=e2t(Y2) 3=t2t(Y2)
    {
        Bin7 B;
        B.r0 = Sr(0); B.c0 = Sc(0); B.v0 = Sv(0);
        B.r1 = Sr(3); B.c1 = Sc(3); B.v1 = Sv(3);
        B.r2 = Sr(5); B.c2 = Sc(5); B.v2 = Sv(5);
        B.r3 = Sr(2); B.c3 = Sc(2); B.v3 = Sv(2);
        B.r4 = B.r3; B.c4 = B.c3; B.v4 = B.v3;
        B.r5 = B.r3; B.c5 = B.c3; B.v5 = B.v3;
        B.r6 = B.r3; B.c6 = B.c3; B.v6 = B.v3;
        B.p1 = Sn(0);
        B.p2 = B.p1 + Sn(3);
        B.p3 = B.p2 + Sn(5);
        B.p4 = B.p3 + Sn(2);
        B.p5 = B.p4; B.p6 = B.p4; B.p7 = B.p4;
        B.t0 = 0; B.t1 = 0; B.t2 = NB0; B.t3 = NB0;
        B.t4 = NB0; B.t5 = NB0; B.t6 = NB0;

        const int chunk = (B.p7 + BIN_GRID - 1) / BIN_GRID;
        hipMemsetAsync(bcount, 0, (size_t)NBtotA * sizeof(int), stream);
        bhist_lds<<<BIN_GRID, 1024, 0, stream>>>(B, bcount, NBtotA, chunk);
        scan_small<<<1, 1024, 0, stream>>>(bcount, boff, bcur, NBtotA);
        scatter_runs<<<BIN_GRID, 1024, 0, stream>>>(B, bcur, bpay, NBtotA, chunk);

        unsigned short* dn2n = dense;
        unsigned short* de2n = dense + (size_t)N0 * 64;
        gemm_powcat_mfma<<<(N0 + 63) / 64, 256, 0, stream>>>(
            X0, N0, 1, wf(0), bp(0), dn2n,
            wf(0), bp(0), dn2n, wf(0), bp(0), dn2n);
        gemm_powcat_mfma<<<(N1 + 63) / 64, 256, 0, stream>>>(
            X1, N1, 1, wf(3), bp(3), de2n,
            wf(3), bp(3), de2n, wf(3), bp(3), de2n);
        spmm_fused7<<<NB0, 256, 0, stream>>>(bpay, boff, bcur,
            dn2n, de2n, dn2n, dn2n, dn2n, dn2n, dn2n,
            out, 0, N0, 1, 1, 0.5f, 0x7F);

        unsigned short* de2t = dense;
        unsigned short* dt2t = dense + (size_t)N1 * 64;
        gemm_powcat_mfma<<<(N1 + 63) / 64, 256, 0, stream>>>(
            X1, N1, 1, wf(4), bp(4), de2t,
            wf(4), bp(4), de2t, wf(4), bp(4), de2t);
        gemm_powcat_mfma<<<(N2 + 63) / 64, 256, 0, stream>>>(
            X2, N2, 1, wf(6), bp(6), dt2t,
            wf(6), bp(6), dt2t, wf(6), bp(6), dt2t);
        spmm_fused7<<<NB2, 256, 0, stream>>>(bpay, boff, bcur,
            de2t, de2t, de2t, dt2t, de2t, de2t, de2t,
            out + offY2, NB0, N2, 1, 1, 0.5f, 0x7F);
    }

    // ---- group B (Y1): did 0=n2e 1=t2e 2=e2e
    {
        Bin7 B;
        B.r0 = Sr(4); B.c0 = Sc(4); B.v0 = Sv(4);
        B.r1 = Sr(6); B.c1 = Sc(6); B.v1 = Sv(6);
        B.r2 = Sr(1); B.c2 = Sc(1); B.v2 = Sv(1);
        B.r3 = B.r2; B.c3 = B.c2; B.v3 = B.v2;
        B.r4 = B.r2; B.c4 = B.c2; B.v4 = B.v2;
        B.r5 = B.r2; B.c5 = B.c2; B.v5 = B.v2;
        B.r6 = B.r2; B.c6 = B.c2; B.v6 = B.v2;
        B.p1 = Sn(4);
        B.p2 = B.p1 + Sn(6);
        B.p3 = B.p2 + Sn(1);
        B.p4 = B.p3; B.p5 = B.p3; B.p6 = B.p3; B.p7 = B.p3;
        B.t0 = 0; B.t1 = 0; B.t2 = 0; B.t3 = 0; B.t4 = 0; B.t5 = 0; B.t6 = 0;

        const int chunk = (B.p7 + BIN_GRID - 1) / BIN_GRID;
        hipMemsetAsync(bcount, 0, (size_t)NB1 * sizeof(int), stream);
        bhist_lds<<<BIN_GRID, 1024, 0, stream>>>(B, bcount, NB1, chunk);
        scan_small<<<1, 1024, 0, stream>>>(bcount, boff, bcur, NB1);
        scatter_runs<<<BIN_GRID, 1024, 0, stream>>>(B, bcur, bpay, NB1, chunk);

        if (fullB) {
            unsigned short* dn2e = dense;
            unsigned short* dt2e = dense + (size_t)N0 * 64;
            unsigned short* de2e = dense + ((size_t)N0 + N2) * 64;
            gemm_powcat_mfma<<<(N0 + 63) / 64, 256, 0, stream>>>(
                X0, N0, 1, wf(1), bp(1), dn2e,
                wf(1), bp(1), dn2e, wf(1), bp(1), dn2e);
            gemm_powcat_mfma<<<(N2 + 63) / 64, 256, 0, stream>>>(
                X2, N2, 1, wf(5), bp(5), dt2e,
                wf(5), bp(5), dt2e, wf(5), bp(5), dt2e);
            gemm_powcat_mfma<<<(N1 + 63) / 64, 256, 0, stream>>>(
                X1, N1, 1, wf(2), bp(2), de2e,
                wf(2), bp(2), de2e, wf(2), bp(2), de2e);
            spmm_fused7<<<NB1, 256, 0, stream>>>(bpay, boff, bcur,
                dn2e, dt2e, de2e, dn2e, dn2e, dn2e, dn2e,
                out + offY1, 0, N1, 1, 1, TH, 0x7F);
        } else {
            unsigned short* dn2e = dense;
            unsigned short* dt2e = dense + (size_t)N0 * 64;
            gemm_powcat_mfma<<<(N0 + 63) / 64, 256, 0, stream>>>(
                X0, N0, 1, wf(1), bp(1), dn2e,
                wf(1), bp(1), dn2e, wf(1), bp(1), dn2e);
            gemm_powcat_mfma<<<(N2 + 63) / 64, 256, 0, stream>>>(
                X2, N2, 1, wf(5), bp(5), dt2e,
                wf(5), bp(5), dt2e, wf(5), bp(5), dt2e);
            spmm_fused7<<<NB1, 256, 0, stream>>>(bpay, boff, bcur,
                dn2e, dt2e, dn2e, dn2e, dn2e, dn2e, dn2e,
                out + offY1, 0, N1, 1, 0, 0.f, 0x3);
            unsigned short* de2e = dense;
            gemm_powcat_mfma<<<(N1 + 63) / 64, 256, 0, stream>>>(
                X1, N1, 1, wf(2), bp(2), de2e,
                wf(2), bp(2), de2e, wf(2), bp(2), de2e);
            spmm_fused7<<<NB1, 256, 0, stream>>>(bpay, boff, bcur,
                de2e, de2e, de2e, de2e, de2e, de2e, de2e,
                out + offY1, 0, N1, 0, 1, TH, 0x4);
        }
    }
}

// Round 2
// 598.071 us; speedup vs baseline: 1.5866x; 1.0917x over previous
//
#include <hip/hip_runtime.h>
#include <hip/hip_bf16.h>

// SCConv: two-level radix binning (pass A: 8-bucket groups with run-reserved
// scatter at full occupancy; pass B: per-group LDS counting sort to final
// 128-row buckets, also emitting boff/bend), 3 fused powcat-GEMMs on MFMA
// (split-bf16 3-term), then one bucketed spmm per output segment.

#define RPB 128
#define CAP 2048
#define COL_MASK 0x7FFFFu
#define LROW_SH 19
#define DID_SH 26
#define MAXNB 4352
#define MAXNG 544
#define GRID_BIN 512

typedef __attribute__((ext_vector_type(8))) short short8;
typedef __attribute__((ext_vector_type(4))) float f32x4;

__device__ __forceinline__ int   ntld_i(const int* p)   { return __builtin_nontemporal_load(p); }
__device__ __forceinline__ float ntld_f(const float* p) { return __builtin_nontemporal_load(p); }
__device__ __forceinline__ float4 ntld_f4(const float* p) {
    const unsigned long long* q = (const unsigned long long*)p;
    unsigned long long a = __builtin_nontemporal_load(q);
    unsigned long long b = __builtin_nontemporal_load(q + 1);
    float4 v;
    v.x = __uint_as_float((unsigned)a);
    v.y = __uint_as_float((unsigned)(a >> 32));
    v.z = __uint_as_float((unsigned)b);
    v.w = __uint_as_float((unsigned)(b >> 32));
    return v;
}
__device__ __forceinline__ void ntst_f4(float* p, float4 v) {
    unsigned long long a = (unsigned long long)__float_as_uint(v.x)
                         | ((unsigned long long)__float_as_uint(v.y) << 32);
    unsigned long long b = (unsigned long long)__float_as_uint(v.z)
                         | ((unsigned long long)__float_as_uint(v.w) << 32);
    unsigned long long* q = (unsigned long long*)p;
    __builtin_nontemporal_store(a, q);
    __builtin_nontemporal_store(b, q + 1);
}

// ---------------- bf16 helpers (RNE) --------------------------------------
__device__ __forceinline__ unsigned short f2bf(float f) {
    unsigned u = __float_as_uint(f);
    unsigned r = u + 0x7FFFu + ((u >> 16) & 1u);
    return (unsigned short)(r >> 16);
}

__device__ __forceinline__ void split8(float4 a0, float4 a1, short8& hi, short8& lo) {
    float v[8] = {a0.x, a0.y, a0.z, a0.w, a1.x, a1.y, a1.z, a1.w};
    #pragma unroll
    for (int e = 0; e < 8; ++e) {
        unsigned short h = f2bf(v[e]);
        float hf = __uint_as_float((unsigned)h << 16);
        hi[e] = (short)h;
        lo[e] = (short)f2bf(v[e] - hf);
    }
}

// ---------------- W -> MFMA B-fragment precompute (once per launch) -------
// Frag layout per set (16384 ushorts = 32KB):
//   [kk(4)][nf(4)][h(2: hi,lo)][lane(64)][e(8)]
// lane l, elem e: k = kk*32 + 8*(l>>4) + e ; col = nf*16 + (l&15)
struct WAll { const float* w[7]; };

__global__ __launch_bounds__(256) void winit(WAll wa, unsigned short* __restrict__ frags)
{
    const int s = blockIdx.x;
    const float* __restrict__ W = wa.w[s];
    unsigned short* __restrict__ out = frags + (size_t)s * 16384;
    for (int slot = threadIdx.x; slot < 1024; slot += 256) {
        const int l  = slot & 63;
        const int nf = (slot >> 6) & 3;
        const int kk = slot >> 8;
        const int col = nf * 16 + (l & 15);
        const int kb  = kk * 32 + 8 * (l >> 4);
        short8 vh, vl;
        #pragma unroll
        for (int e = 0; e < 8; ++e) {
            float w = W[(size_t)(kb + e) * 64 + col];
            unsigned short h = f2bf(w);
            float hf = __uint_as_float((unsigned)h << 16);
            vh[e] = (short)h;
            vl[e] = (short)f2bf(w - hf);
        }
        *(short8*)(out + ((size_t)((kk * 4 + nf) * 2 + 0) * 64 + l) * 8) = vh;
        *(short8*)(out + ((size_t)((kk * 4 + nf) * 2 + 1) * 64 + l) * 8) = vl;
    }
}

// ---------------- MFMA powcat-GEMM (up to 3 weight sets per X) ------------
__device__ __forceinline__ void mfma_set(
    const short8 Ah[4], const short8 Al[4],
    const unsigned short* __restrict__ F, const float* __restrict__ bias,
    unsigned short* __restrict__ D, int nrows, int row0w, int l)
{
    const int lg = l >> 4, lr = l & 15;
    const short8* __restrict__ Fv = (const short8*)F;
    f32x4 acc[4];
    #pragma unroll
    for (int nf = 0; nf < 4; ++nf) {
        float b = bias[nf * 16 + lr];
        f32x4 bi = {b, b, b, b};
        acc[nf] = bi;
    }
    #pragma unroll
    for (int kk = 0; kk < 4; ++kk) {
        #pragma unroll
        for (int nf = 0; nf < 4; ++nf) {
            short8 bh = Fv[((kk * 4 + nf) * 2 + 0) * 64 + l];
            short8 bl = Fv[((kk * 4 + nf) * 2 + 1) * 64 + l];
            acc[nf] = __builtin_amdgcn_mfma_f32_16x16x32_bf16(Ah[kk], bh, acc[nf], 0, 0, 0);
            acc[nf] = __builtin_amdgcn_mfma_f32_16x16x32_bf16(Al[kk], bh, acc[nf], 0, 0, 0);
            acc[nf] = __builtin_amdgcn_mfma_f32_16x16x32_bf16(Ah[kk], bl, acc[nf], 0, 0, 0);
        }
    }
    #pragma unroll
    for (int nf = 0; nf < 4; ++nf) {
        #pragma unroll
        for (int j = 0; j < 4; ++j) {
            int row = row0w + lg * 4 + j;   // C/D: col=lane&15, row=4*(lane>>4)+reg
            if (row < nrows)
                D[(size_t)row * 64 + nf * 16 + lr] = f2bf(acc[nf][j]);
        }
    }
}

__global__ __launch_bounds__(256) void gemm_powcat_mfma(
    const float* __restrict__ X, int nrows, int nsets,
    const unsigned short* __restrict__ F0, const float* __restrict__ b0, unsigned short* __restrict__ D0,
    const unsigned short* __restrict__ F1, const float* __restrict__ b1, unsigned short* __restrict__ D1,
    const unsigned short* __restrict__ F2, const float* __restrict__ b2, unsigned short* __restrict__ D2)
{
    __shared__ float Xs[64][68];   // pad stride 68 -> balanced LDS banks
    const int tid = threadIdx.x;
    const int row0 = blockIdx.x * 64;

    #pragma unroll
    for (int it = 0; it < 4; ++it) {
        int idx = tid + it * 256;
        int r = idx >> 4, c4 = idx & 15;
        float4 v = make_float4(0.f, 0.f, 0.f, 0.f);
        if (row0 + r < nrows)
            v = ntld_f4(X + (size_t)(row0 + r) * 64 + c4 * 4);
        *(float4*)&Xs[r][c4 * 4] = v;
    }
    __syncthreads();

    const int w = tid >> 6, l = tid & 63;
    const int lg = l >> 4, lr = l & 15;

    // A-frags (shared across all weight sets): powcat K=128 = [X | X^2]
    short8 Ah[4], Al[4];
    #pragma unroll
    for (int kk = 0; kk < 4; ++kk) {
        const float* p = &Xs[w * 16 + lr][(kk & 1) * 32 + 8 * lg];
        float4 a0 = *(const float4*)p;
        float4 a1 = *(const float4*)(p + 4);
        if (kk >= 2) {
            a0.x *= a0.x; a0.y *= a0.y; a0.z *= a0.z; a0.w *= a0.w;
            a1.x *= a1.x; a1.y *= a1.y; a1.z *= a1.z; a1.w *= a1.w;
        }
        split8(a0, a1, Ah[kk], Al[kk]);
    }

    const int row0w = row0 + w * 16;
    mfma_set(Ah, Al, F0, b0, D0, nrows, row0w, l);
    if (nsets > 1) mfma_set(Ah, Al, F1, b1, D1, nrows, row0w, l);
    if (nsets > 2) mfma_set(Ah, Al, F2, b2, D2, nrows, row0w, l);
}

// ---------------- 7-slot flat COO view ------------------------------------
struct Bin7 {
    const int *r0, *r1, *r2, *r3, *r4, *r5, *r6;
    const int *c0, *c1, *c2, *c3, *c4, *c5, *c6;
    const float *v0, *v1, *v2, *v3, *v4, *v5, *v6;
    int p1, p2, p3, p4, p5, p6, p7;   // cumulative prefix ends
    int t0, t1, t2, t3, t4, t5, t6;   // bucket-tile base per slot
};

struct Ent { int r; int tb; unsigned cw; float v; };

template<bool FULL>
__device__ __forceinline__ Ent decode(const Bin7& B, int i) {
    Ent e;
    if (i < B.p1) {
        int li = i;
        e.r = ntld_i(B.r0 + li); e.tb = B.t0;
        if (FULL) { e.cw = (unsigned)ntld_i(B.c0 + li) | (0u << DID_SH); e.v = ntld_f(B.v0 + li); }
    } else if (i < B.p2) {
        int li = i - B.p1;
        e.r = ntld_i(B.r1 + li); e.tb = B.t1;
        if (FULL) { e.cw = (unsigned)ntld_i(B.c1 + li) | (1u << DID_SH); e.v = ntld_f(B.v1 + li); }
    } else if (i < B.p3) {
        int li = i - B.p2;
        e.r = ntld_i(B.r2 + li); e.tb = B.t2;
        if (FULL) { e.cw = (unsigned)ntld_i(B.c2 + li) | (2u << DID_SH); e.v = ntld_f(B.v2 + li); }
    } else if (i < B.p4) {
        int li = i - B.p3;
        e.r = ntld_i(B.r3 + li); e.tb = B.t3;
        if (FULL) { e.cw = (unsigned)ntld_i(B.c3 + li) | (3u << DID_SH); e.v = ntld_f(B.v3 + li); }
    } else if (i < B.p5) {
        int li = i - B.p4;
        e.r = ntld_i(B.r4 + li); e.tb = B.t4;
        if (FULL) { e.cw = (unsigned)ntld_i(B.c4 + li) | (4u << DID_SH); e.v = ntld_f(B.v4 + li); }
    } else if (i < B.p6) {
        int li = i - B.p5;
        e.r = ntld_i(B.r5 + li); e.tb = B.t5;
        if (FULL) { e.cw = (unsigned)ntld_i(B.c5 + li) | (5u << DID_SH); e.v = ntld_f(B.v5 + li); }
    } else {
        int li = i - B.p6;
        e.r = ntld_i(B.r6 + li); e.tb = B.t6;
        if (FULL) { e.cw = (unsigned)ntld_i(B.c6 + li) | (6u << DID_SH); e.v = ntld_f(B.v6 + li); }
    }
    return e;
}

// ---------------- group histogram (8 buckets per group) -------------------
__global__ __launch_bounds__(1024) void bhist_grp(
    Bin7 B, int* __restrict__ gcount, int NG, int chunk)
{
    __shared__ int h[MAXNG];
    for (int i = threadIdx.x; i < NG; i += 1024) h[i] = 0;
    __syncthreads();
    const int s = blockIdx.x * chunk;
    int e = s + chunk;  if (e > B.p7) e = B.p7;
    for (int i = s + threadIdx.x; i < e; i += 1024) {
        Ent en = decode<false>(B, i);
        atomicAdd(&h[(en.tb + (en.r >> 7)) >> 3], 1);
    }
    __syncthreads();
    for (int i = threadIdx.x; i < NG; i += 1024)
        if (h[i]) atomicAdd(&gcount[i], h[i]);
}

// ---------------- pass A: run-reserved scatter into group segments --------
// payA word: col(19) | lrow(7)<<19 | (bucket&7)<<26 | did<<29
__global__ __launch_bounds__(1024) void scatter_grp(
    Bin7 B, int* __restrict__ gcur, uint2* __restrict__ payA,
    int NG, int chunk)
{
    __shared__ int lbase[MAXNG];
    __shared__ int lcur[MAXNG];
    for (int i = threadIdx.x; i < NG; i += 1024) lcur[i] = 0;
    __syncthreads();
    const int s = blockIdx.x * chunk;
    int e = s + chunk;  if (e > B.p7) e = B.p7;

    for (int i = s + threadIdx.x; i < e; i += 1024) {
        Ent en = decode<false>(B, i);
        atomicAdd(&lcur[(en.tb + (en.r >> 7)) >> 3], 1);
    }
    __syncthreads();
    for (int i = threadIdx.x; i < NG; i += 1024) {
        int c = lcur[i];
        lbase[i] = c ? atomicAdd(&gcur[i], c) : 0;
        lcur[i] = 0;
    }
    __syncthreads();
    for (int i = s + threadIdx.x; i < e; i += 1024) {
        Ent en = decode<true>(B, i);
        int b = en.tb + (en.r >> 7);
        int g = b >> 3;
        int pos = lbase[g] + atomicAdd(&lcur[g], 1);
        unsigned col = en.cw & COL_MASK;
        unsigned did = en.cw >> DID_SH;
        unsigned cwA = col | ((unsigned)(en.r & 127) << LROW_SH)
                     | ((unsigned)(b & 7) << 26) | (did << 29);
        payA[pos] = make_uint2(cwA, __float_as_uint(en.v));
    }
}

// ---------------- pass B: per-group counting sort to final buckets --------
// Also derives and writes boff/bend per final bucket.
__global__ __launch_bounds__(1024) void sort_grp(
    const uint2* __restrict__ payA, const int* __restrict__ goff,
    const int* __restrict__ gcur, int* __restrict__ boff,
    int* __restrict__ bend, uint2* __restrict__ payB, int NBtot)
{
    __shared__ int cnt[8], cur[8];
    const int g = blockIdx.x;
    const int b0 = g * 8;
    const int seg0 = goff[g], seg1 = gcur[g];
    if (threadIdx.x < 8) cnt[threadIdx.x] = 0;
    __syncthreads();
    for (int i = seg0 + threadIdx.x; i < seg1; i += 1024) {
        unsigned w = __builtin_nontemporal_load(&payA[i].x);
        atomicAdd(&cnt[(w >> 26) & 7], 1);
    }
    __syncthreads();
    if (threadIdx.x == 0) {
        int base = seg0;
        #pragma unroll
        for (int j = 0; j < 8; ++j) {
            cur[j] = base;
            if (b0 + j < NBtot) { boff[b0 + j] = base; bend[b0 + j] = base + cnt[j]; }
            base += cnt[j];
        }
    }
    __syncthreads();
    for (int i = seg0 + threadIdx.x; i < seg1; i += 1024) {
        unsigned long long pv = __builtin_nontemporal_load(
            (const unsigned long long*)(payA + i));
        unsigned w = (unsigned)pv;
        int j = (w >> 26) & 7;
        int pos = atomicAdd(&cur[j], 1);
        unsigned cw = (w & 0x03FFFFFFu) | ((w >> 29) << 26);
        payB[pos] = make_uint2(cw, (unsigned)(pv >> 32));
    }
}

// ---------------- shfl-based single-block exclusive scan ------------------
__global__ __launch_bounds__(1024) void scan_small(
    const int* __restrict__ in, int* __restrict__ boff,
    int* __restrict__ bcur, int n)
{
    __shared__ int wsum[16];
    __shared__ int carry;
    const int tid = threadIdx.x, lane = tid & 63, wv = tid >> 6;
    if (tid == 0) carry = 0;
    __syncthreads();
    for (int base = 0; base < n; base += 4096) {
        int i = base + tid * 4;
        int v0 = (i + 0 < n) ? in[i + 0] : 0;
        int v1 = (i + 1 < n) ? in[i + 1] : 0;
        int v2 = (i + 2 < n) ? in[i + 2] : 0;
        int v3 = (i + 3 < n) ? in[i + 3] : 0;
        int tsum = v0 + v1 + v2 + v3;
        int x = tsum;
        #pragma unroll
        for (int off = 1; off < 64; off <<= 1) {
            int y = __shfl_up(x, off);
            if (lane >= off) x += y;
        }
        if (lane == 63) wsum[wv] = x;
        int c0 = carry;
        __syncthreads();
        if (tid < 16) {
            int ss = wsum[tid];
            #pragma unroll
            for (int off = 1; off < 16; off <<= 1) {
                int y = __shfl_up(ss, off, 16);
                if (tid >= off) ss += y;
            }
            wsum[tid] = ss;
        }
        __syncthreads();
        int wpre = (wv == 0) ? 0 : wsum[wv - 1];
        int excl = c0 + wpre + (x - tsum);
        if (i + 0 < n) { boff[i + 0] = excl; bcur[i + 0] = excl; } excl += v0;
        if (i + 1 < n) { boff[i + 1] = excl; bcur[i + 1] = excl; } excl += v1;
        if (i + 2 < n) { boff[i + 2] = excl; bcur[i + 2] = excl; } excl += v2;
        if (i + 3 < n) { boff[i + 3] = excl; bcur[i + 3] = excl; }
        __syncthreads();
        if (tid == 0) carry = c0 + wsum[15];
        __syncthreads();
    }
}

// ---------------- bucketed SpMM (single segment per bucket) ---------------
__global__ __launch_bounds__(256) void spmm_fused7(
    const uint2* __restrict__ bpay, const int* __restrict__ boff,
    const int* __restrict__ bend,
    const unsigned short* __restrict__ d0, const unsigned short* __restrict__ d1,
    const unsigned short* __restrict__ d2, const unsigned short* __restrict__ d3,
    const unsigned short* __restrict__ d4, const unsigned short* __restrict__ d5,
    const unsigned short* __restrict__ d6,
    float* __restrict__ out, int tile0, int nrows,
    int firstWrite, int doRelu, float scale, int didMask)
{
    __shared__ uint2 pay[CAP];            // 16 KB
    __shared__ unsigned short sidx[CAP];  // 4 KB
    __shared__ int lcount[128], loff[128], lcur[128];
    __shared__ int s_w0;
    __shared__ const unsigned short* dptr[8];

    const int tid = threadIdx.x;
    const int t = tile0 + blockIdx.x;

    if (tid == 0) {
        dptr[0] = d0; dptr[1] = d1; dptr[2] = d2; dptr[3] = d3;
        dptr[4] = d4; dptr[5] = d5; dptr[6] = d6; dptr[7] = d0;
    }
    __syncthreads();

    const int seg0  = boff[t];
    const int total = bend[t] - seg0;
    const int nchunks = (total + CAP - 1) / CAP;
    const int qw = tid >> 4, l = tid & 15;
    const int row0 = blockIdx.x * RPB;

    float4 acc[8];
    #pragma unroll
    for (int rr = 0; rr < 8; ++rr) acc[rr] = make_float4(0.f, 0.f, 0.f, 0.f);

    for (int c = 0; c < nchunks; ++c) {
        if (tid < 128) lcount[tid] = 0;
        __syncthreads();

        const int cbase = c * CAP;
        int ccnt = total - cbase;
        if (ccnt > CAP) ccnt = CAP;

        for (int i = tid; i < ccnt; i += 256) {
            unsigned long long pv = __builtin_nontemporal_load(
                (const unsigned long long*)(bpay + seg0 + cbase + i));
            uint2 p = make_uint2((unsigned)pv, (unsigned)(pv >> 32));
            pay[i] = p;
            atomicAdd(&lcount[(p.x >> LROW_SH) & 127], 1);
        }
        __syncthreads();

        int xv = 0;
        if (tid < 128) xv = lcount[tid];
        #pragma unroll
        for (int off = 1; off < 64; off <<= 1) {
            int y = __shfl_up(xv, off);
            if ((tid & 63) >= off) xv += y;
        }
        if (tid == 63) s_w0 = xv;
        __syncthreads();
        if (tid < 128) {
            int incl = xv + ((tid >= 64) ? s_w0 : 0);
            loff[tid] = incl - lcount[tid];
            lcur[tid] = incl - lcount[tid];
        }
        __syncthreads();

        for (int i = tid; i < ccnt; i += 256) {
            int lr = (pay[i].x >> LROW_SH) & 127;
            int pos = atomicAdd(&lcur[lr], 1);
            sidx[pos] = (unsigned short)i;
        }
        __syncthreads();

        #pragma unroll
        for (int rr = 0; rr < 8; ++rr) {
            int lr = rr * 16 + qw;
            int ss = loff[lr], ee = ss + lcount[lr];
            float4 a = acc[rr];
            for (int j = ss; j < ee; ++j) {
                uint2 p = pay[sidx[j]];
                int did = (int)(p.x >> DID_SH) & 7;
                if (!((didMask >> did) & 1)) continue;
                int col = p.x & COL_MASK;
                float v = __uint_as_float(p.y);
                const uint2* Dg = reinterpret_cast<const uint2*>(dptr[did]);
                uint2 d = Dg[(size_t)col * 16 + l];
                a.x = fmaf(v, __uint_as_float((d.x & 0xFFFFu) << 16), a.x);
                a.y = fmaf(v, __uint_as_float(d.x & 0xFFFF0000u), a.y);
                a.z = fmaf(v, __uint_as_float((d.y & 0xFFFFu) << 16), a.z);
                a.w = fmaf(v, __uint_as_float(d.y & 0xFFFF0000u), a.w);
            }
            acc[rr] = a;
        }
        __syncthreads();
    }

    #pragma unroll
    for (int rr = 0; rr < 8; ++rr) {
        int lr = rr * 16 + qw;
        int row = row0 + lr;
        if (row < nrows) {
            float* o = out + (size_t)row * 64 + l * 4;
            float4 a = acc[rr];
            if (!firstWrite) {
                float4 cur = *reinterpret_cast<float4*>(o);
                a.x += cur.x; a.y += cur.y; a.z += cur.z; a.w += cur.w;
            }
            if (doRelu) {
                a.x = fmaxf(a.x, 0.f) * scale;
                a.y = fmaxf(a.y, 0.f) * scale;
                a.z = fmaxf(a.z, 0.f) * scale;
                a.w = fmaxf(a.w, 0.f) * scale;
            }
            ntst_f4(o, a);
        }
    }
}

extern "C" void kernel_launch(void* const* d_in, const int* in_sizes, int n_in,
                              void* d_out, int out_size, void* d_ws, size_t ws_size,
                              hipStream_t stream)
{
    const float* X0 = (const float*)d_in[0];
    const float* X1 = (const float*)d_in[1];
    const float* X2 = (const float*)d_in[2];
    const int N0 = in_sizes[0] / 64;
    const int N1 = in_sizes[1] / 64;
    const int N2 = in_sizes[2] / 64;

    auto Wp = [&](int i) { return (const float*)d_in[24 + 2 * i]; };
    auto bp = [&](int i) { return (const float*)d_in[25 + 2 * i]; };
    auto Sr = [&](int i) { return (const int*)d_in[3 + 3 * i]; };
    auto Sc = [&](int i) { return (const int*)d_in[4 + 3 * i]; };
    auto Sv = [&](int i) { return (const float*)d_in[5 + 3 * i]; };
    auto Sn = [&](int i) { return in_sizes[3 + 3 * i]; };

    const size_t offY1 = (size_t)N0 * 64;
    const size_t offY2 = (size_t)(N0 + N1) * 64;
    const float TH = 1.0f / 3.0f;

    const int NB0 = (N0 + RPB - 1) / RPB;
    const int NB1 = (N1 + RPB - 1) / RPB;
    const int NB2 = (N2 + RPB - 1) / RPB;

    float* out = (float*)d_out;
    auto align256 = [](size_t x) { return (x + 255) & ~(size_t)255; };

    // -------- W fragment precompute (all 7 sets, once) --------
    const size_t FRAG_SET = 16384;  // ushorts per set (32 KB)
    const size_t fragB = align256(7 * FRAG_SET * sizeof(unsigned short));
    if (ws_size <= fragB) return;   // pathological; cannot run
    unsigned short* wfrags = (unsigned short*)d_ws;
    char* ws = (char*)d_ws + fragB;
    const size_t ws_avail = ws_size - fragB;
    auto wf = [&](int i) { return wfrags + (size_t)i * FRAG_SET; };

    WAll wa;
    for (int i = 0; i < 7; ++i) wa.w[i] = Wp(i);
    winit<<<7, 256, 0, stream>>>(wa, wfrags);

    // -------- tier 1: everything at once --------
    const int NBall = NB0 + NB1 + NB2;
    const int NGall = (NBall + 7) / 8;
    const int nnzAll = Sn(0)+Sn(1)+Sn(2)+Sn(3)+Sn(4)+Sn(5)+Sn(6);
    const size_t payAsz = (size_t)nnzAll * sizeof(uint2);
    const size_t payT1 = align256(payAsz);
    const size_t cntT1 = align256((size_t)(NBall + 8) * sizeof(int));
    const size_t denseT1 = ((size_t)2*N0 + 3*N1 + 2*N2) * 64 * sizeof(unsigned short);
    const size_t regionT1 = denseT1 > payT1 ? denseT1 : payT1;  // dense ∪ payA
    const size_t needT1 = payT1 + 5 * cntT1 + regionT1;

    if (ws_avail >= needT1 && NBall <= MAXNB) {
        uint2* payB  = (uint2*)ws;
        int* goff    = (int*)(ws + payT1);
        int* gcur    = (int*)(ws + payT1 + 1 * cntT1);
        int* boff    = (int*)(ws + payT1 + 2 * cntT1);
        int* bend    = (int*)(ws + payT1 + 3 * cntT1);
        int* gcount  = (int*)(ws + payT1 + 4 * cntT1);
        char* region = ws + payT1 + 5 * cntT1;
        uint2* payA  = (uint2*)region;               // dead after sort_grp
        unsigned short* db = (unsigned short*)region; // gemms write after sort_grp
        unsigned short* dn2n = db;
        unsigned short* de2n = dn2n + (size_t)N0 * 64;
        unsigned short* dn2e = de2n + (size_t)N1 * 64;
        unsigned short* de2e = dn2e + (size_t)N0 * 64;
        unsigned short* dt2e = de2e + (size_t)N1 * 64;
        unsigned short* de2t = dt2e + (size_t)N2 * 64;
        unsigned short* dt2t = de2t + (size_t)N1 * 64;

        Bin7 B;
        // did: 0 n2n(L0) 1 e2n(D1invB1) 2 n2e(D2B1TD1inv) 3 e2e(L1) 4 t2e(B2D3) 5 e2t(B2TD2inv) 6 t2t(L2)
        B.r0 = Sr(0); B.c0 = Sc(0); B.v0 = Sv(0);
        B.r1 = Sr(3); B.c1 = Sc(3); B.v1 = Sv(3);
        B.r2 = Sr(4); B.c2 = Sc(4); B.v2 = Sv(4);
        B.r3 = Sr(1); B.c3 = Sc(1); B.v3 = Sv(1);
        B.r4 = Sr(6); B.c4 = Sc(6); B.v4 = Sv(6);
        B.r5 = Sr(5); B.c5 = Sc(5); B.v5 = Sv(5);
        B.r6 = Sr(2); B.c6 = Sc(2); B.v6 = Sv(2);
        B.p1 = Sn(0);
        B.p2 = B.p1 + Sn(3);
        B.p3 = B.p2 + Sn(4);
        B.p4 = B.p3 + Sn(1);
        B.p5 = B.p4 + Sn(6);
        B.p6 = B.p5 + Sn(5);
        B.p7 = B.p6 + Sn(2);
        B.t0 = 0;   B.t1 = 0;
        B.t2 = NB0; B.t3 = NB0; B.t4 = NB0;
        B.t5 = NB0 + NB1; B.t6 = NB0 + NB1;

        const int chunk = (B.p7 + GRID_BIN - 1) / GRID_BIN;
        hipMemsetAsync(gcount, 0, (size_t)NGall * sizeof(int), stream);
        bhist_grp<<<GRID_BIN, 1024, 0, stream>>>(B, gcount, NGall, chunk);
        scan_small<<<1, 1024, 0, stream>>>(gcount, goff, gcur, NGall);
        scatter_grp<<<GRID_BIN, 1024, 0, stream>>>(B, gcur, payA, NGall, chunk);
        sort_grp<<<NGall, 1024, 0, stream>>>(payA, goff, gcur, boff, bend, payB, NBall);

        gemm_powcat_mfma<<<(N0 + 63) / 64, 256, 0, stream>>>(
            X0, N0, 2,
            wf(0), bp(0), dn2n,
            wf(1), bp(1), dn2e,
            wf(0), bp(0), dn2n);
        gemm_powcat_mfma<<<(N1 + 63) / 64, 256, 0, stream>>>(
            X1, N1, 3,
            wf(3), bp(3), de2n,
            wf(2), bp(2), de2e,
            wf(4), bp(4), de2t);
        gemm_powcat_mfma<<<(N2 + 63) / 64, 256, 0, stream>>>(
            X2, N2, 2,
            wf(5), bp(5), dt2e,
            wf(6), bp(6), dt2t,
            wf(5), bp(5), dt2e);

        spmm_fused7<<<NB0, 256, 0, stream>>>(payB, boff, bend,
            dn2n, de2n, dn2e, de2e, dt2e, de2t, dt2t,
            out, 0, N0, 1, 1, 0.5f, 0x7F);
        spmm_fused7<<<NB1, 256, 0, stream>>>(payB, boff, bend,
            dn2n, de2n, dn2e, de2e, dt2e, de2t, dt2t,
            out + offY1, NB0, N1, 1, 1, TH, 0x7F);
        spmm_fused7<<<NB2, 256, 0, stream>>>(payB, boff, bend,
            dn2n, de2n, dn2e, de2e, dt2e, de2t, dt2t,
            out + offY2, NB0 + NB1, N2, 1, 1, 0.5f, 0x7F);
        return;
    }

    // -------- tier 2: two-group phased layout (same kernels) --------
    const int NBtotA = NB0 + NB2;
    const int NBmax = NBtotA > NB1 ? NBtotA : NB1;
    const int nnzA = Sn(0) + Sn(3) + Sn(5) + Sn(2);
    const int nnzB = Sn(4) + Sn(6) + Sn(1);
    const int nnzMax = nnzA > nnzB ? nnzA : nnzB;

    const size_t payBsz = align256((size_t)nnzMax * sizeof(uint2));
    const size_t cntB = align256((size_t)(NBmax + 8) * sizeof(int));
    const size_t denseOff = payBsz + 5 * cntB;

    uint2* bpayB = (uint2*)ws;
    int* goff    = (int*)(ws + payBsz);
    int* gcur    = (int*)(ws + payBsz + 1 * cntB);
    int* boff    = (int*)(ws + payBsz + 2 * cntB);
    int* bend    = (int*)(ws + payBsz + 3 * cntB);
    int* gcount  = (int*)(ws + payBsz + 4 * cntB);
    unsigned short* dense = (unsigned short*)(ws + denseOff);
    uint2* payA  = (uint2*)dense;   // transient, dead before gemms write dense

    const size_t need_full = denseOff +
        ((size_t)N0 + N2 + N1) * 64 * sizeof(unsigned short);
    const bool fullB = (ws_avail >= need_full);

    // ---- group A: did 0=n2n(Y0) 1=e2n(Y0) 2=e2t(Y2) 3=t2t(Y2)
    {
        Bin7 B;
        B.r0 = Sr(0); B.c0 = Sc(0); B.v0 = Sv(0);
        B.r1 = Sr(3); B.c1 = Sc(3); B.v1 = Sv(3);
        B.r2 = Sr(5); B.c2 = Sc(5); B.v2 = Sv(5);
        B.r3 = Sr(2); B.c3 = Sc(2); B.v3 = Sv(2);
        B.r4 = B.r3; B.c4 = B.c3; B.v4 = B.v3;
        B.r5 = B.r3; B.c5 = B.c3; B.v5 = B.v3;
        B.r6 = B.r3; B.c6 = B.c3; B.v6 = B.v3;
        B.p1 = Sn(0);
        B.p2 = B.p1 + Sn(3);
        B.p3 = B.p2 + Sn(5);
        B.p4 = B.p3 + Sn(2);
        B.p5 = B.p4; B.p6 = B.p4; B.p7 = B.p4;
        B.t0 = 0; B.t1 = 0; B.t2 = NB0; B.t3 = NB0;
        B.t4 = NB0; B.t5 = NB0; B.t6 = NB0;

        const int NGA = (NBtotA + 7) / 8;
        const int chunk = (B.p7 + GRID_BIN - 1) / GRID_BIN;
        hipMemsetAsync(gcount, 0, (size_t)NGA * sizeof(int), stream);
        bhist_grp<<<GRID_BIN, 1024, 0, stream>>>(B, gcount, NGA, chunk);
        scan_small<<<1, 1024, 0, stream>>>(gcount, goff, gcur, NGA);
        scatter_grp<<<GRID_BIN, 1024, 0, stream>>>(B, gcur, payA, NGA, chunk);
        sort_grp<<<NGA, 1024, 0, stream>>>(payA, goff, gcur, boff, bend, bpayB, NBtotA);

        unsigned short* dn2n = dense;
        unsigned short* de2n = dense + (size_t)N0 * 64;
        gemm_powcat_mfma<<<(N0 + 63) / 64, 256, 0, stream>>>(
            X0, N0, 1, wf(0), bp(0), dn2n,
            wf(0), bp(0), dn2n, wf(0), bp(0), dn2n);
        gemm_powcat_mfma<<<(N1 + 63) / 64, 256, 0, stream>>>(
            X1, N1, 1, wf(3), bp(3), de2n,
            wf(3), bp(3), de2n, wf(3), bp(3), de2n);
        spmm_fused7<<<NB0, 256, 0, stream>>>(bpayB, boff, bend,
            dn2n, de2n, dn2n, dn2n, dn2n, dn2n, dn2n,
            out, 0, N0, 1, 1, 0.5f, 0x7F);

        unsigned short* de2t = dense;
        unsigned short* dt2t = dense + (size_t)N1 * 64;
        gemm_powcat_mfma<<<(N1 + 63) / 64, 256, 0, stream>>>(
            X1, N1, 1, wf(4), bp(4), de2t,
            wf(4), bp(4), de2t, wf(4), bp(4), de2t);
        gemm_powcat_mfma<<<(N2 + 63) / 64, 256, 0, stream>>>(
            X2, N2, 1, wf(6), bp(6), dt2t,
            wf(6), bp(6), dt2t, wf(6), bp(6), dt2t);
        spmm_fused7<<<NB2, 256, 0, stream>>>(bpayB, boff, bend,
            de2t, de2t, de2t, dt2t, de2t, de2t, de2t,
            out + offY2, NB0, N2, 1, 1, 0.5f, 0x7F);
    }

    // ---- group B (Y1): did 0=n2e 1=t2e 2=e2e
    {
        Bin7 B;
        B.r0 = Sr(4); B.c0 = Sc(4); B.v0 = Sv(4);
        B.r1 = Sr(6); B.c1 = Sc(6); B.v1 = Sv(6);
        B.r2 = Sr(1); B.c2 = Sc(1); B.v2 = Sv(1);
        B.r3 = B.r2; B.c3 = B.c2; B.v3 = B.v2;
        B.r4 = B.r2; B.c4 = B.c2; B.v4 = B.v2;
        B.r5 = B.r2; B.c5 = B.c2; B.v5 = B.v2;
        B.r6 = B.r2; B.c6 = B.c2; B.v6 = B.v2;
        B.p1 = Sn(4);
        B.p2 = B.p1 + Sn(6);
        B.p3 = B.p2 + Sn(1);
        B.p4 = B.p3; B.p5 = B.p3; B.p6 = B.p3; B.p7 = B.p3;
        B.t0 = 0; B.t1 = 0; B.t2 = 0; B.t3 = 0; B.t4 = 0; B.t5 = 0; B.t6 = 0;

        const int NGB = (NB1 + 7) / 8;
        const int chunk = (B.p7 + GRID_BIN - 1) / GRID_BIN;
        hipMemsetAsync(gcount, 0, (size_t)NGB * sizeof(int), stream);
        bhist_grp<<<GRID_BIN, 1024, 0, stream>>>(B, gcount, NGB, chunk);
        scan_small<<<1, 1024, 0, stream>>>(gcount, goff, gcur, NGB);
        scatter_grp<<<GRID_BIN, 1024, 0, stream>>>(B, gcur, payA, NGB, chunk);
        sort_grp<<<NGB, 1024, 0, stream>>>(payA, goff, gcur, boff, bend, bpayB, NB1);

        if (fullB) {
            unsigned short* dn2e = dense;
            unsigned short* dt2e = dense + (size_t)N0 * 64;
            unsigned short* de2e = dense + ((size_t)N0 + N2) * 64;
            gemm_powcat_mfma<<<(N0 + 63) / 64, 256, 0, stream>>>(
                X0, N0, 1, wf(1), bp(1), dn2e,
                wf(1), bp(1), dn2e, wf(1), bp(1), dn2e);
            gemm_powcat_mfma<<<(N2 + 63) / 64, 256, 0, stream>>>(
                X2, N2, 1, wf(5), bp(5), dt2e,
                wf(5), bp(5), dt2e, wf(5), bp(5), dt2e);
            gemm_powcat_mfma<<<(N1 + 63) / 64, 256, 0, stream>>>(
                X1, N1, 1, wf(2), bp(2), de2e,
                wf(2), bp(2), de2e, wf(2), bp(2), de2e);
            spmm_fused7<<<NB1, 256, 0, stream>>>(bpayB, boff, bend,
                dn2e, dt2e, de2e, dn2e, dn2e, dn2e, dn2e,
                out + offY1, 0, N1, 1, 1, TH, 0x7F);
        } else {
            unsigned short* dn2e = dense;
            unsigned short* dt2e = dense + (size_t)N0 * 64;
            gemm_powcat_mfma<<<(N0 + 63) / 64, 256, 0, stream>>>(
                X0, N0, 1, wf(1), bp(1), dn2e,
                wf(1), bp(1), dn2e, wf(1), bp(1), dn2e);
            gemm_powcat_mfma<<<(N2 + 63) / 64, 256, 0, stream>>>(
                X2, N2, 1, wf(5), bp(5), dt2e,
                wf(5), bp(5), dt2e, wf(5), bp(5), dt2e);
            spmm_fused7<<<NB1, 256, 0, stream>>>(bpayB, boff, bend,
                dn2e, dt2e, dn2e, dn2e, dn2e, dn2e, dn2e,
                out + offY1, 0, N1, 1, 0, 0.f, 0x3);
            unsigned short* de2e = dense;
            gemm_powcat_mfma<<<(N1 + 63) / 64, 256, 0, stream>>>(
                X1, N1, 1, wf(2), bp(2), de2e,
                wf(2), bp(2), de2e, wf(2), bp(2), de2e);
            spmm_fused7<<<NB1, 256, 0, stream>>>(bpayB, boff, bend,
                de2e, de2e, de2e, de2e, de2e, de2e, de2e,
                out + offY1, 0, N1, 0, 1, TH, 0x4);
        }
    }
}